// Round 3
// baseline (348.980 us; speedup 1.0000x reference)
//
#include <hip/hip_runtime.h>
#include <stdint.h>

#define BATCH 32
#define TLEN  1024
#define DIN   512
#define DOUT  512
#define KW    5
#define TOUT  1020          // TLEN - KW + 1
#define KDIM  (DIN * KW)    // 2560

#define BM 128
#define BN 128
#define BK 128              // A-tile K-depth; LDS rows 256 B, 16 chunks, XOR-swizzled

typedef __attribute__((ext_vector_type(8))) short bf16x8;
typedef __attribute__((ext_vector_type(4))) float f32x4;

__device__ __forceinline__ uint16_t f2bf(float f) {
    uint32_t u = __float_as_uint(f);
    uint32_t r = u + 0x7FFFu + ((u >> 16) & 1u);   // RNE to bf16
    return (uint16_t)(r >> 16);
}

// Fused prep:
//  blocks [0,8192):    convert x fp32 -> xb bf16, 8 elem/thread, exact
//  blocks [8192,8704): o = bid-8192; pack W[o,:,:] -> Wb[o][k*512+i]
//                      coalesced read + LDS transpose + coalesced write
__global__ void convert_pack(const float4* __restrict__ x, uint4* __restrict__ xb,
                             const float* __restrict__ w, uint16_t* __restrict__ wb) {
    __shared__ uint16_t sW[KDIM];      // 5 KB, used by pack path only
    int bid = blockIdx.x;
    if (bid < 8192) {
        int idx = bid * 256 + threadIdx.x;          // 0 .. 2097151 exact
        float4 a = x[2 * idx];
        float4 b = x[2 * idx + 1];
        uint4 v;
        v.x = (uint32_t)f2bf(a.x) | ((uint32_t)f2bf(a.y) << 16);
        v.y = (uint32_t)f2bf(a.z) | ((uint32_t)f2bf(a.w) << 16);
        v.z = (uint32_t)f2bf(b.x) | ((uint32_t)f2bf(b.y) << 16);
        v.w = (uint32_t)f2bf(b.z) | ((uint32_t)f2bf(b.w) << 16);
        xb[idx] = v;
    } else {
        int o = bid - 8192;                         // 0..511
        #pragma unroll
        for (int r = 0; r < 10; ++r) {
            int idx = r * 256 + threadIdx.x;        // flat (i,k) = i*5+k, coalesced
            sW[idx] = f2bf(w[o * KDIM + idx]);
        }
        __syncthreads();
        #pragma unroll
        for (int r = 0; r < 10; ++r) {
            int kk = r * 256 + threadIdx.x;         // output index k*512+i, coalesced
            int i = kk & 511;
            int k = kk >> 9;
            wb[o * KDIM + kk] = sW[i * 5 + k];
        }
    }
}

// GEMM: C[m=(b,t), n=o] = sum_k xflat[b, t*512+k] * Wb[n][k]
// A staged via global_load_lds into 256-B LDS rows, 16-slot XOR swizzle.
// B fragments loaded DIRECTLY from global (Wb row-major == MFMA B-frag layout):
// no LDS, no barrier dependency -> compiler pipelines them against MFMA.
__global__ void __launch_bounds__(256, 4)
tdnn_gemm(const uint16_t* __restrict__ xb,
          const uint16_t* __restrict__ wb,
          const float* __restrict__ bias,
          float* __restrict__ out) {
    __shared__ uint16_t As[BM * BK];   // 32 KB

    // XCD-aware swizzle: the 4 nb-blocks of one A-tile differ by 8 -> same XCD.
    const int j    = blockIdx.x;       // 0..1023
    const int xcd  = j & 7;
    const int nb   = (j >> 3) & 3;
    const int gi   = j >> 5;           // 0..31
    const int g    = gi * 8 + xcd;     // 0..255
    const int b    = g >> 3;
    const int tb   = g & 7;
    const int t0   = tb * BM;
    const int n0   = nb * BN;

    const int tid  = threadIdx.x;
    const int lane = tid & 63;
    const int w    = tid >> 6;
    const int m_wave = (w & 1) * 64;
    const int n_wave = (w >> 1) * 64;

    const uint16_t* xrow = xb + (size_t)b * TLEN * DIN + (size_t)t0 * DIN;

    const int ml = lane & 15;
    const int kg = lane >> 4;          // 0..3

    // Per-ni B fragment base pointers: row = n0+n_wave+ni*16+ml, k-chunk = kg*8
    const uint16_t* bp0 = wb + (size_t)(n0 + n_wave +  0 + ml) * KDIM + kg * 8;
    const uint16_t* bp1 = wb + (size_t)(n0 + n_wave + 16 + ml) * KDIM + kg * 8;
    const uint16_t* bp2 = wb + (size_t)(n0 + n_wave + 32 + ml) * KDIM + kg * 8;
    const uint16_t* bp3 = wb + (size_t)(n0 + n_wave + 48 + ml) * KDIM + kg * 8;

    f32x4 acc[4][4] = {};

    for (int kb = 0; kb < KDIM; kb += BK) {
        // ---- stage A: 128 rows x 256 B = 2048 chunks of 16 B, 8 per lane ----
        #pragma unroll
        for (int i = 0; i < 8; ++i) {
            int c    = w * 512 + i * 64 + lane;
            int row  = c >> 4;
            int slot = c & 15;
            int ccg  = slot ^ (row & 15);
            const uint16_t* gp = xrow + row * DIN + kb + ccg * 8;
            const uint16_t* lp = &As[(w * 512 + i * 64) * 8];  // wave-uniform base
            __builtin_amdgcn_global_load_lds(
                (const __attribute__((address_space(1))) void*)gp,
                (__attribute__((address_space(3))) void*)lp, 16, 0, 0);
        }
        __syncthreads();

        #pragma unroll
        for (int h = 0; h < 4; ++h) {
            const int cc = h * 4 + kg;          // 16B-chunk within 256-B row
            // B fragments straight from global (L1/L2-resident)
            bf16x8 bfr[4];
            bfr[0] = *(const bf16x8*)(bp0 + kb + h * 32);
            bfr[1] = *(const bf16x8*)(bp1 + kb + h * 32);
            bfr[2] = *(const bf16x8*)(bp2 + kb + h * 32);
            bfr[3] = *(const bf16x8*)(bp3 + kb + h * 32);
            bf16x8 af[4];
            #pragma unroll
            for (int mi = 0; mi < 4; ++mi) {
                int r = m_wave + mi * 16 + ml;
                af[mi] = *(const bf16x8*)&As[r * BK + ((cc ^ (r & 15)) * 8)];
            }
            #pragma unroll
            for (int mi = 0; mi < 4; ++mi)
                #pragma unroll
                for (int ni = 0; ni < 4; ++ni)
                    acc[mi][ni] = __builtin_amdgcn_mfma_f32_16x16x32_bf16(
                        af[mi], bfr[ni], acc[mi][ni], 0, 0, 0);
        }
        __syncthreads();
    }

    // ---- epilogue: D map: col=lane&15, row=(lane>>4)*4+r ----
    const int rq = (lane >> 4) * 4;
    #pragma unroll
    for (int ni = 0; ni < 4; ++ni) {
        int o = n0 + n_wave + ni * 16 + ml;
        float bv = bias[o];
        float* orow = out + ((size_t)b * DOUT + o) * TOUT;
        #pragma unroll
        for (int mi = 0; mi < 4; ++mi) {
            int tbase = t0 + m_wave + mi * 16 + rq;
            #pragma unroll
            for (int r = 0; r < 4; ++r) {
                int t = tbase + r;
                if (t < TOUT) {
                    float v = acc[mi][ni][r] + bv;
                    orow[t] = v > 0.0f ? v : 0.0f;
                }
            }
        }
    }
}

extern "C" void kernel_launch(void* const* d_in, const int* in_sizes, int n_in,
                              void* d_out, int out_size, void* d_ws, size_t ws_size,
                              hipStream_t stream) {
    const float* x    = (const float*)d_in[0];
    const float* wgt  = (const float*)d_in[1];
    const float* bias = (const float*)d_in[2];
    float* out = (float*)d_out;

    // ws layout: xb first (b=31 tail over-read lands in wb, not OOB)
    uint16_t* xb = (uint16_t*)d_ws;                                   // 33.55 MB
    uint16_t* wb = (uint16_t*)((char*)d_ws + (size_t)BATCH * TLEN * DIN * 2);

    convert_pack<<<8704, 256, 0, stream>>>((const float4*)x, (uint4*)xb, wgt, wb);
    tdnn_gemm<<<1024, 256, 0, stream>>>(xb, wb, bias, out);
}

// Round 4
// 223.881 us; speedup vs baseline: 1.5588x; 1.5588x over previous
//
#include <hip/hip_runtime.h>
#include <stdint.h>

#define BATCH 32
#define TLEN  1024
#define DIN   512
#define DOUT  512
#define KW    5
#define TOUT  1020          // TLEN - KW + 1
#define KDIM  (DIN * KW)    // 2560

#define BM 128
#define BN 128
#define BKI 128             // i-chunk staged per barrier phase (4 chunks total)
#define AROWS 144           // staged x rows: 128 outputs + 4 taps (+12 pad for exact grid)

typedef __attribute__((ext_vector_type(8))) short bf16x8;
typedef __attribute__((ext_vector_type(4))) float f32x4;

__device__ __forceinline__ uint16_t f2bf(float f) {
    uint32_t u = __float_as_uint(f);
    uint32_t r = u + 0x7FFFu + ((u >> 16) & 1u);   // RNE to bf16
    return (uint16_t)(r >> 16);
}

// blocks [0,8192): convert x fp32 -> xb bf16, 8 elem/thread, exact
// blocks [8192,13312): pack W -> Wb2 in MFMA B-FRAGMENT order:
//   fragment f = c*80 + j  (c = n/16, j = k/32, k = tap*512 + i)
//   lane l of fragment holds W'[n = c*16 + (l&15)][k = j*32 + (l>>4)*8 + e], e=0..7
//   Wb2[f*512 + l*8 + e]  -> B-frag load is base + f*1024B + lane*16B (coalesced)
__global__ void convert_pack(const float4* __restrict__ x, uint4* __restrict__ xb,
                             const float* __restrict__ w, uint16_t* __restrict__ wb2) {
    int bid = blockIdx.x;
    if (bid < 8192) {
        int idx = bid * 256 + threadIdx.x;          // 0 .. 2097151 exact
        float4 a = x[2 * idx];
        float4 b = x[2 * idx + 1];
        uint4 v;
        v.x = (uint32_t)f2bf(a.x) | ((uint32_t)f2bf(a.y) << 16);
        v.y = (uint32_t)f2bf(a.z) | ((uint32_t)f2bf(a.w) << 16);
        v.z = (uint32_t)f2bf(b.x) | ((uint32_t)f2bf(b.y) << 16);
        v.w = (uint32_t)f2bf(b.z) | ((uint32_t)f2bf(b.w) << 16);
        xb[idx] = v;
    } else {
        int idx = (bid - 8192) * 256 + threadIdx.x; // 0 .. 1310719 exact
        int f = idx >> 9;           // fragment id
        int l = (idx >> 3) & 63;    // lane within fragment
        int e = idx & 7;            // element within lane's 16 B
        int c = f / 80;
        int j = f - c * 80;
        int n = c * 16 + (l & 15);
        int k = j * 32 + ((l >> 4) * 8) + e;
        int tap = k >> 9;
        int i   = k & 511;
        wb2[idx] = f2bf(w[(n * DIN + i) * KW + tap]);
    }
}

// C[m=(b,t), n=o] = sum_{tap,i} x[b, t+tap, i] * W[o, i, tap]
// A: x rows staged ONCE per i-chunk (conv structure; taps = row-shifted frags).
// B: loaded directly from pre-fragmented Wb2 (coalesced, L2-resident, no LDS,
//    no barrier coupling -> pipelines against MFMA).
__global__ void __launch_bounds__(256, 4)
tdnn_gemm(const uint16_t* __restrict__ xb,
          const uint16_t* __restrict__ wb2,
          const float* __restrict__ bias,
          float* __restrict__ out) {
    __shared__ uint16_t As[AROWS * BKI];   // 36 KB; rows 256 B, 16-slot XOR swizzle

    // XCD-aware swizzle: the 4 nb-blocks of one A-tile differ by 8 -> same XCD.
    const int j    = blockIdx.x;       // 0..1023
    const int xcd  = j & 7;
    const int nb   = (j >> 3) & 3;
    const int gi   = j >> 5;           // 0..31
    const int g    = gi * 8 + xcd;     // 0..255
    const int b    = g >> 3;
    const int tb   = g & 7;
    const int t0   = tb * BM;
    const int n0   = nb * BN;

    const int tid  = threadIdx.x;
    const int lane = tid & 63;
    const int w    = tid >> 6;
    const int m_wave = (w & 1) * 64;
    const int n_wave = (w >> 1) * 64;

    const uint16_t* xrow = xb + (size_t)b * TLEN * DIN + (size_t)t0 * DIN;

    const int ml = lane & 15;
    const int kg = lane >> 4;          // 0..3

    // B fragment stream base: c = (n0+n_wave)/16 + ni ; frag = c*80 + tap*16 + ic*4 + h
    const int c0 = (n0 + n_wave) >> 4;
    const uint16_t* bbase = wb2 + (size_t)c0 * 80 * 512 + (size_t)lane * 8;

    f32x4 acc[4][4] = {};

    for (int ic = 0; ic < 4; ++ic) {
        const int i0 = ic * BKI;
        // ---- stage A: 144 rows x 256 B = 2304 chunks of 16 B, 9/lane exact ----
        #pragma unroll
        for (int it = 0; it < 9; ++it) {
            int c    = w * 576 + it * 64 + lane;
            int row  = c >> 4;
            int slot = c & 15;
            int ccg  = slot ^ (row & 15);
            const uint16_t* gp = xrow + row * DIN + i0 + ccg * 8;
            const uint16_t* lp = &As[(w * 576 + it * 64) * 8];  // wave-uniform base
            __builtin_amdgcn_global_load_lds(
                (const __attribute__((address_space(1))) void*)gp,
                (__attribute__((address_space(3))) void*)lp, 16, 0, 0);
        }
        __syncthreads();

        #pragma unroll
        for (int tap = 0; tap < KW; ++tap) {
            #pragma unroll
            for (int h = 0; h < 4; ++h) {
                const int cc = h * 4 + kg;          // 16B chunk within 256-B row
                // B frags: coalesced 1 KB wave loads from L2-resident Wb2
                const size_t foff = (size_t)(tap * 16 + ic * 4 + h) * 512;
                bf16x8 bfr[4];
                #pragma unroll
                for (int ni = 0; ni < 4; ++ni)
                    bfr[ni] = *(const bf16x8*)(bbase + (size_t)ni * 80 * 512 + foff);
                // A frags: row-shifted by tap, XOR-swizzled slots
                bf16x8 af[4];
                #pragma unroll
                for (int mi = 0; mi < 4; ++mi) {
                    int r = m_wave + mi * 16 + ml + tap;
                    af[mi] = *(const bf16x8*)&As[r * BKI + ((cc ^ (r & 15)) * 8)];
                }
                #pragma unroll
                for (int mi = 0; mi < 4; ++mi)
                    #pragma unroll
                    for (int ni = 0; ni < 4; ++ni)
                        acc[mi][ni] = __builtin_amdgcn_mfma_f32_16x16x32_bf16(
                            af[mi], bfr[ni], acc[mi][ni], 0, 0, 0);
            }
        }
        __syncthreads();
    }

    // ---- epilogue: D map: col=lane&15, row=(lane>>4)*4+r ----
    const int rq = (lane >> 4) * 4;
    #pragma unroll
    for (int ni = 0; ni < 4; ++ni) {
        int o = n0 + n_wave + ni * 16 + ml;
        float bv = bias[o];
        float* orow = out + ((size_t)b * DOUT + o) * TOUT;
        #pragma unroll
        for (int mi = 0; mi < 4; ++mi) {
            int tbase = t0 + m_wave + mi * 16 + rq;
            #pragma unroll
            for (int r = 0; r < 4; ++r) {
                int t = tbase + r;
                if (t < TOUT) {
                    float v = acc[mi][ni][r] + bv;
                    orow[t] = v > 0.0f ? v : 0.0f;
                }
            }
        }
    }
}

extern "C" void kernel_launch(void* const* d_in, const int* in_sizes, int n_in,
                              void* d_out, int out_size, void* d_ws, size_t ws_size,
                              hipStream_t stream) {
    const float* x    = (const float*)d_in[0];
    const float* wgt  = (const float*)d_in[1];
    const float* bias = (const float*)d_in[2];
    float* out = (float*)d_out;

    // ws layout: xb first -> the b=31/tb=7 staged tail over-read (<17 KB past
    // xb end) lands inside wb2 (allocated, values discarded by store guard).
    uint16_t* xb  = (uint16_t*)d_ws;                                  // 33.55 MB
    uint16_t* wb2 = (uint16_t*)((char*)d_ws + (size_t)BATCH * TLEN * DIN * 2);

    convert_pack<<<13312, 256, 0, stream>>>((const float4*)x, (uint4*)xb, wgt, wb2);
    tdnn_gemm<<<1024, 256, 0, stream>>>(xb, wb2, bias, out);
}